// Round 12
// baseline (216.194 us; speedup 1.0000x reference)
//
#include <hip/hip_runtime.h>
#include <stdint.h>

// r12: single lever vs r11 — k_pv v3 = m97-style global_load_lds staging,
// LINEAR source + LINEAR dest (r6's failure was a swizzled source), BK=64,
// LDS 32KB. qk/prep byte-identical to r11 => delta(total) = delta(pv).
// Trusted ledger (r11 anchor): qk=76.5, pv=121, prep=5.

// ---------- types ----------
typedef __bf16 bf16x8 __attribute__((ext_vector_type(8)));
typedef unsigned short u16x8 __attribute__((ext_vector_type(8)));
typedef float f32x4 __attribute__((ext_vector_type(4)));

#define SM_SCALE 4.419417382415922e-02f /* 1/22.627416997969522 */
#define DROP_SCALE (1.0f / 0.9f)

// ---------- helpers ----------
__device__ __forceinline__ unsigned short f2bf(float f) {
  uint32_t u = __float_as_uint(f);
  uint32_t r = (u + 0x7FFFu + ((u >> 16) & 1u)) >> 16;  // RNE
  return (unsigned short)r;
}
__device__ __forceinline__ float bf2f(unsigned short h) {
  return __uint_as_float(((uint32_t)h) << 16);
}

// async global->LDS, 16B/lane. LDS dest = wave-uniform base + lane*16.
__device__ __forceinline__ void async16(const void* g, void* l) {
  __builtin_amdgcn_global_load_lds(
      (__attribute__((address_space(1))) uint32_t*)g,
      (__attribute__((address_space(3))) uint32_t*)l, 16, 0, 0);
}

// JAX threefry2x32 with key (0,42). [validated r4]
__device__ __forceinline__ void threefry2x32(uint32_t x0, uint32_t x1,
                                             uint32_t& o0, uint32_t& o1) {
  const uint32_t K0 = 0u, K1 = 42u;
  const uint32_t K2 = K0 ^ K1 ^ 0x1BD11BDAu;
  x0 += K0; x1 += K1;
#define TF_R(rot) { x0 += x1; x1 = (x1 << rot) | (x1 >> (32 - rot)); x1 ^= x0; }
  TF_R(13) TF_R(15) TF_R(26) TF_R(6)  x0 += K1; x1 += K2 + 1u;
  TF_R(17) TF_R(29) TF_R(16) TF_R(24) x0 += K2; x1 += K0 + 2u;
  TF_R(13) TF_R(15) TF_R(26) TF_R(6)  x0 += K0; x1 += K1 + 3u;
  TF_R(17) TF_R(29) TF_R(16) TF_R(24) x0 += K1; x1 += K2 + 4u;
  TF_R(13) TF_R(15) TF_R(26) TF_R(6)  x0 += K2; x1 += K0 + 5u;
#undef TF_R
  o0 = x0; o1 = x1;
}

// keep-mask, JAX partitionable threefry, ctr=(0,idx), XOR-fold. [validated r4]
__device__ __forceinline__ bool drop_keep(uint32_t idx) {
  uint32_t o0, o1;
  threefry2x32(0u, idx, o0, o1);
  uint32_t bits = o0 ^ o1;
  float u = __uint_as_float((bits >> 9) | 0x3f800000u) - 1.0f;  // [0,1)
  return u < 0.9f;
}

// ---------- kernel 1: value[512][4096] f32 -> valueT[4096][512] bf16 [validated r4] ----
__global__ __launch_bounds__(256) void k_vt(const float* __restrict__ v,
                                            unsigned short* __restrict__ vt) {
  __shared__ float tile[32][33];
  const int nb = blockIdx.x;   // 0..127
  const int kb = blockIdx.y;   // 0..15
  const int tx = threadIdx.x & 31, ty = threadIdx.x >> 5;  // 32 x 8
#pragma unroll
  for (int yy = 0; yy < 4; ++yy) {
    int row = ty + yy * 8;
    tile[row][tx] = v[(size_t)(kb * 32 + row) * 4096 + nb * 32 + tx];
  }
  __syncthreads();
#pragma unroll
  for (int yy = 0; yy < 4; ++yy) {
    int row = ty + yy * 8;
    vt[(size_t)(nb * 32 + row) * 512 + kb * 32 + tx] = f2bf(tile[tx][row]);
  }
}

// ---------- kernel 1b: in2 f32 -> bf16 hi/lo split [validated r5] ----------
__global__ __launch_bounds__(256) void k_split(const float* __restrict__ src,
                                               unsigned short* __restrict__ hi,
                                               unsigned short* __restrict__ lo,
                                               int n4) {
  int i = blockIdx.x * 256 + threadIdx.x;
  if (i >= n4) return;
  float4 v = reinterpret_cast<const float4*>(src)[i];
  ushort4 h, l;
  h.x = f2bf(v.x); l.x = f2bf(v.x - bf2f(h.x));
  h.y = f2bf(v.y); l.y = f2bf(v.y - bf2f(h.y));
  h.z = f2bf(v.z); l.z = f2bf(v.z - bf2f(h.z));
  h.w = f2bf(v.w); l.w = f2bf(v.w - bf2f(h.w));
  reinterpret_cast<ushort4*>(hi)[i] = h;
  reinterpret_cast<ushort4*>(lo)[i] = l;
}

// ---------- kernel 2: QK^T (split-bf16 MFMA) + softmax + dropout -> P bf16 ----------
// [v2 exact bytes — measured 76.5us]
__global__ __launch_bounds__(512) void k_qk(const float* __restrict__ in1,
                                            const unsigned short* __restrict__ B2hi,
                                            const unsigned short* __restrict__ B2lo,
                                            unsigned short* __restrict__ P) {
  __shared__ unsigned short lB[512][72];  // [col][hi 0..31 | lo 32..63 | pad] 73.7KB
  __shared__ float redm[4][32], reds[4][32];

  const int tid = threadIdx.x;
  const int l = tid & 63, w = tid >> 6;
  const int wr = w >> 2, wc = w & 3;      // wave grid 2 x 4
  const int g = l >> 4, c16 = l & 15;
  const int brow = blockIdx.x * 32;

  f32x4 acc[8] = {};

  for (int kt = 0; kt < 16; ++kt) {
    const int k0 = kt * 32;
    // ---- stage B hi+lo tile [512 cols][32 k] each ----
#pragma unroll
    for (int i = 0; i < 8; ++i) {
      int c = i * 512 + tid;                // 4096 chunks of 8 shorts
      int col = c >> 3, half = (c >> 2) & 1, sub = c & 3;
      const unsigned short* src = (half ? B2lo : B2hi) + (size_t)col * 512 + k0 + sub * 8;
      *reinterpret_cast<u16x8*>(&lB[col][half * 32 + sub * 8]) =
          *reinterpret_cast<const u16x8*>(src);
    }
    // ---- A fragment direct from global, split in-register ----
    const int arow = brow + wr * 16 + c16;
    float4 v0 = *reinterpret_cast<const float4*>(in1 + (size_t)arow * 512 + k0 + g * 8);
    float4 v1 = *reinterpret_cast<const float4*>(in1 + (size_t)arow * 512 + k0 + g * 8 + 4);
    bf16x8 ahi, alo;
    {
      float vv[8] = {v0.x, v0.y, v0.z, v0.w, v1.x, v1.y, v1.z, v1.w};
      unsigned short h[8], lo8[8];
#pragma unroll
      for (int e = 0; e < 8; ++e) {
        h[e] = f2bf(vv[e]);
        lo8[e] = f2bf(vv[e] - bf2f(h[e]));
      }
      ahi = *reinterpret_cast<const bf16x8*>(h);
      alo = *reinterpret_cast<const bf16x8*>(lo8);
    }
    __syncthreads();
#pragma unroll
    for (int j = 0; j < 8; ++j) {
      const int col = wc * 128 + j * 16 + c16;
      bf16x8 bh = *reinterpret_cast<const bf16x8*>(&lB[col][g * 8]);
      bf16x8 bl = *reinterpret_cast<const bf16x8*>(&lB[col][32 + g * 8]);
      acc[j] = __builtin_amdgcn_mfma_f32_16x16x32_bf16(ahi, bh, acc[j], 0, 0, 0);
      acc[j] = __builtin_amdgcn_mfma_f32_16x16x32_bf16(alo, bh, acc[j], 0, 0, 0);
      acc[j] = __builtin_amdgcn_mfma_f32_16x16x32_bf16(ahi, bl, acc[j], 0, 0, 0);
    }
    __syncthreads();
  }

  // ---- epilogue: scale, softmax over 512 cols, dropout, write P bf16 ----
  const int rowbase = wr * 16 + g * 4;
  float mx[4] = {-3.4e38f, -3.4e38f, -3.4e38f, -3.4e38f};
#pragma unroll
  for (int j = 0; j < 8; ++j)
#pragma unroll
    for (int r = 0; r < 4; ++r) {
      acc[j][r] *= SM_SCALE;
      mx[r] = fmaxf(mx[r], acc[j][r]);
    }
#pragma unroll
  for (int s = 1; s < 16; s <<= 1)
#pragma unroll
    for (int r = 0; r < 4; ++r) mx[r] = fmaxf(mx[r], __shfl_xor(mx[r], s, 64));
  if (c16 == 0) {
#pragma unroll
    for (int r = 0; r < 4; ++r) redm[wc][rowbase + r] = mx[r];
  }
  __syncthreads();
  float rmax[4], sum[4] = {0.f, 0.f, 0.f, 0.f};
#pragma unroll
  for (int r = 0; r < 4; ++r)
    rmax[r] = fmaxf(fmaxf(redm[0][rowbase + r], redm[1][rowbase + r]),
                    fmaxf(redm[2][rowbase + r], redm[3][rowbase + r]));
#pragma unroll
  for (int j = 0; j < 8; ++j)
#pragma unroll
    for (int r = 0; r < 4; ++r) {
      float e = expf(acc[j][r] - rmax[r]);
      acc[j][r] = e;
      sum[r] += e;
    }
#pragma unroll
  for (int s = 1; s < 16; s <<= 1)
#pragma unroll
    for (int r = 0; r < 4; ++r) sum[r] += __shfl_xor(sum[r], s, 64);
  if (c16 == 0) {
#pragma unroll
    for (int r = 0; r < 4; ++r) reds[wc][rowbase + r] = sum[r];
  }
  __syncthreads();
  float scl[4];
#pragma unroll
  for (int r = 0; r < 4; ++r)
    scl[r] = DROP_SCALE / (reds[0][rowbase + r] + reds[1][rowbase + r] +
                           reds[2][rowbase + r] + reds[3][rowbase + r]);

#pragma unroll
  for (int j = 0; j < 8; ++j) {
    const int col = wc * 128 + j * 16 + c16;
#pragma unroll
    for (int r = 0; r < 4; ++r) {
      uint32_t idx = (uint32_t)(brow + rowbase + r) * 512u + (uint32_t)col;
      float pv = drop_keep(idx) ? acc[j][r] * scl[r] : 0.0f;
      P[idx] = f2bf(pv);
    }
  }
}

// ---------- kernel 3: out = P[16384][512] @ vT[4096][512]^T (bf16 MFMA) ----------
// v3: m97-style. 128x128 tile, BK=64, 4 waves (2x2). global_load_lds width=16,
// LINEAR source (coalesced) + LINEAR LDS dest [128][64]. LDS 32KB total.
__global__ __launch_bounds__(256) void k_pv(const unsigned short* __restrict__ P,
                                            const unsigned short* __restrict__ VT,
                                            float* __restrict__ out) {
  __shared__ unsigned short lA[128 * 64];  // 16KB, linear [row][64]
  __shared__ unsigned short lB[128 * 64];  // 16KB
  const int tid = threadIdx.x;
  const int l = tid & 63, w = tid >> 6;
  const int wr = w >> 1, wc = w & 1;
  const int g = l >> 4, c16 = l & 15;

  // XCD-aware bijective swizzle (4096 % 8 == 0)
  const int bid = blockIdx.x;
  const int x = (bid & 7) * 512 + (bid >> 3);
  const int brow = (x >> 5) * 128;   // 128 row-tiles
  const int bcol = (x & 31) * 128;   // 32 col-tiles

  f32x4 acc[4][4] = {};

  for (int kt = 0; kt < 8; ++kt) {
    const int k0 = kt * 64;
    // stage both tiles: 1024 chunks of 16B each, linear order (coalesced)
#pragma unroll
    for (int i = 0; i < 4; ++i) {
      int c = i * 256 + tid;            // chunk id: row = c>>3, sub = c&7
      int row = c >> 3, sub = c & 7;
      async16(P + (size_t)(brow + row) * 512 + k0 + sub * 8,
              lA + (size_t)(i * 256 + w * 64) * 8);
      async16(VT + (size_t)(bcol + row) * 512 + k0 + sub * 8,
              lB + (size_t)(i * 256 + w * 64) * 8);
    }
    asm volatile("s_waitcnt vmcnt(0)" ::: "memory");
    __syncthreads();

#pragma unroll
    for (int kk = 0; kk < 64; kk += 32) {
      bf16x8 a[4], b[4];
#pragma unroll
      for (int i = 0; i < 4; ++i) {
        int row = wr * 64 + i * 16 + c16;
        a[i] = *reinterpret_cast<const bf16x8*>(lA + row * 64 + kk + g * 8);
      }
#pragma unroll
      for (int j = 0; j < 4; ++j) {
        int row = wc * 64 + j * 16 + c16;
        b[j] = *reinterpret_cast<const bf16x8*>(lB + row * 64 + kk + g * 8);
      }
#pragma unroll
      for (int i = 0; i < 4; ++i)
#pragma unroll
        for (int j = 0; j < 4; ++j)
          acc[i][j] = __builtin_amdgcn_mfma_f32_16x16x32_bf16(a[i], b[j], acc[i][j], 0, 0, 0);
    }
    __syncthreads();
  }

  // C/D layout (validated r4): col = lane&15, row = (lane>>4)*4 + reg
#pragma unroll
  for (int i = 0; i < 4; ++i)
#pragma unroll
    for (int r = 0; r < 4; ++r) {
      const size_t row = (size_t)(brow + wr * 64 + i * 16 + g * 4 + r);
      float* o = out + row * 4096 + bcol + wc * 64 + c16;
#pragma unroll
      for (int j = 0; j < 4; ++j) o[j * 16] = acc[i][j][r];
    }
}

// ---------- launch ----------
extern "C" void kernel_launch(void* const* d_in, const int* in_sizes, int n_in,
                              void* d_out, int out_size, void* d_ws, size_t ws_size,
                              hipStream_t stream) {
  (void)in_sizes; (void)n_in; (void)out_size; (void)ws_size;
  const float* in1   = (const float*)d_in[0];   // [16384][512]
  const float* in2   = (const float*)d_in[1];   // [512][512]
  const float* value = (const float*)d_in[2];   // [512][4096]
  float* out = (float*)d_out;                   // [16384][4096]

  unsigned short* vT    = (unsigned short*)d_ws;  // 4 MB   [4096][512] bf16
  unsigned short* Pb    = vT + 2097152;           // 16 MB  [16384][512] bf16
  unsigned short* in2hi = Pb + 8388608;           // 0.5 MB [512][512] bf16
  unsigned short* in2lo = in2hi + 262144;         // 0.5 MB

  k_vt<<<dim3(128, 16), dim3(256), 0, stream>>>(value, vT);
  k_split<<<dim3(256), dim3(256), 0, stream>>>(in2, in2hi, in2lo, 65536);
  k_qk<<<dim3(512), dim3(512), 0, stream>>>(in1, in2hi, in2lo, Pb);
  k_pv<<<dim3(4096), dim3(256), 0, stream>>>(Pb, vT, out);
}

// Round 13
// 208.039 us; speedup vs baseline: 1.0392x; 1.0392x over previous
//
#include <hip/hip_runtime.h>
#include <stdint.h>

// r13: single lever vs r11 — k_pv v4 = 256x256 tile, BK=32, reg-staged padded
// LDS (proven mechanism), 512 thr / 8 waves. Halves tile read traffic:
// 1 GB -> 512 MB (P 16MB x16 + vT 4MB x64). qk/prep byte-identical to r11.
// Ledger: pv = dur - 81.5 (qk 76.5 + prep 5).

// ---------- types ----------
typedef __bf16 bf16x8 __attribute__((ext_vector_type(8)));
typedef unsigned short u16x8 __attribute__((ext_vector_type(8)));
typedef float f32x4 __attribute__((ext_vector_type(4)));

#define SM_SCALE 4.419417382415922e-02f /* 1/22.627416997969522 */
#define DROP_SCALE (1.0f / 0.9f)

// ---------- helpers ----------
__device__ __forceinline__ unsigned short f2bf(float f) {
  uint32_t u = __float_as_uint(f);
  uint32_t r = (u + 0x7FFFu + ((u >> 16) & 1u)) >> 16;  // RNE
  return (unsigned short)r;
}
__device__ __forceinline__ float bf2f(unsigned short h) {
  return __uint_as_float(((uint32_t)h) << 16);
}

// JAX threefry2x32 with key (0,42). [validated r4]
__device__ __forceinline__ void threefry2x32(uint32_t x0, uint32_t x1,
                                             uint32_t& o0, uint32_t& o1) {
  const uint32_t K0 = 0u, K1 = 42u;
  const uint32_t K2 = K0 ^ K1 ^ 0x1BD11BDAu;
  x0 += K0; x1 += K1;
#define TF_R(rot) { x0 += x1; x1 = (x1 << rot) | (x1 >> (32 - rot)); x1 ^= x0; }
  TF_R(13) TF_R(15) TF_R(26) TF_R(6)  x0 += K1; x1 += K2 + 1u;
  TF_R(17) TF_R(29) TF_R(16) TF_R(24) x0 += K2; x1 += K0 + 2u;
  TF_R(13) TF_R(15) TF_R(26) TF_R(6)  x0 += K0; x1 += K1 + 3u;
  TF_R(17) TF_R(29) TF_R(16) TF_R(24) x0 += K1; x1 += K2 + 4u;
  TF_R(13) TF_R(15) TF_R(26) TF_R(6)  x0 += K2; x1 += K0 + 5u;
#undef TF_R
  o0 = x0; o1 = x1;
}

// keep-mask, JAX partitionable threefry, ctr=(0,idx), XOR-fold. [validated r4]
__device__ __forceinline__ bool drop_keep(uint32_t idx) {
  uint32_t o0, o1;
  threefry2x32(0u, idx, o0, o1);
  uint32_t bits = o0 ^ o1;
  float u = __uint_as_float((bits >> 9) | 0x3f800000u) - 1.0f;  // [0,1)
  return u < 0.9f;
}

// ---------- kernel 1: value[512][4096] f32 -> valueT[4096][512] bf16 [validated r4] ----
__global__ __launch_bounds__(256) void k_vt(const float* __restrict__ v,
                                            unsigned short* __restrict__ vt) {
  __shared__ float tile[32][33];
  const int nb = blockIdx.x;   // 0..127
  const int kb = blockIdx.y;   // 0..15
  const int tx = threadIdx.x & 31, ty = threadIdx.x >> 5;  // 32 x 8
#pragma unroll
  for (int yy = 0; yy < 4; ++yy) {
    int row = ty + yy * 8;
    tile[row][tx] = v[(size_t)(kb * 32 + row) * 4096 + nb * 32 + tx];
  }
  __syncthreads();
#pragma unroll
  for (int yy = 0; yy < 4; ++yy) {
    int row = ty + yy * 8;
    vt[(size_t)(nb * 32 + row) * 512 + kb * 32 + tx] = f2bf(tile[tx][row]);
  }
}

// ---------- kernel 1b: in2 f32 -> bf16 hi/lo split [validated r5] ----------
__global__ __launch_bounds__(256) void k_split(const float* __restrict__ src,
                                               unsigned short* __restrict__ hi,
                                               unsigned short* __restrict__ lo,
                                               int n4) {
  int i = blockIdx.x * 256 + threadIdx.x;
  if (i >= n4) return;
  float4 v = reinterpret_cast<const float4*>(src)[i];
  ushort4 h, l;
  h.x = f2bf(v.x); l.x = f2bf(v.x - bf2f(h.x));
  h.y = f2bf(v.y); l.y = f2bf(v.y - bf2f(h.y));
  h.z = f2bf(v.z); l.z = f2bf(v.z - bf2f(h.z));
  h.w = f2bf(v.w); l.w = f2bf(v.w - bf2f(h.w));
  reinterpret_cast<ushort4*>(hi)[i] = h;
  reinterpret_cast<ushort4*>(lo)[i] = l;
}

// ---------- kernel 2: QK^T (split-bf16 MFMA) + softmax + dropout -> P bf16 ----------
// [v2 exact bytes — measured 76.5us]
__global__ __launch_bounds__(512) void k_qk(const float* __restrict__ in1,
                                            const unsigned short* __restrict__ B2hi,
                                            const unsigned short* __restrict__ B2lo,
                                            unsigned short* __restrict__ P) {
  __shared__ unsigned short lB[512][72];  // [col][hi 0..31 | lo 32..63 | pad] 73.7KB
  __shared__ float redm[4][32], reds[4][32];

  const int tid = threadIdx.x;
  const int l = tid & 63, w = tid >> 6;
  const int wr = w >> 2, wc = w & 3;      // wave grid 2 x 4
  const int g = l >> 4, c16 = l & 15;
  const int brow = blockIdx.x * 32;

  f32x4 acc[8] = {};

  for (int kt = 0; kt < 16; ++kt) {
    const int k0 = kt * 32;
    // ---- stage B hi+lo tile [512 cols][32 k] each ----
#pragma unroll
    for (int i = 0; i < 8; ++i) {
      int c = i * 512 + tid;                // 4096 chunks of 8 shorts
      int col = c >> 3, half = (c >> 2) & 1, sub = c & 3;
      const unsigned short* src = (half ? B2lo : B2hi) + (size_t)col * 512 + k0 + sub * 8;
      *reinterpret_cast<u16x8*>(&lB[col][half * 32 + sub * 8]) =
          *reinterpret_cast<const u16x8*>(src);
    }
    // ---- A fragment direct from global, split in-register ----
    const int arow = brow + wr * 16 + c16;
    float4 v0 = *reinterpret_cast<const float4*>(in1 + (size_t)arow * 512 + k0 + g * 8);
    float4 v1 = *reinterpret_cast<const float4*>(in1 + (size_t)arow * 512 + k0 + g * 8 + 4);
    bf16x8 ahi, alo;
    {
      float vv[8] = {v0.x, v0.y, v0.z, v0.w, v1.x, v1.y, v1.z, v1.w};
      unsigned short h[8], lo8[8];
#pragma unroll
      for (int e = 0; e < 8; ++e) {
        h[e] = f2bf(vv[e]);
        lo8[e] = f2bf(vv[e] - bf2f(h[e]));
      }
      ahi = *reinterpret_cast<const bf16x8*>(h);
      alo = *reinterpret_cast<const bf16x8*>(lo8);
    }
    __syncthreads();
#pragma unroll
    for (int j = 0; j < 8; ++j) {
      const int col = wc * 128 + j * 16 + c16;
      bf16x8 bh = *reinterpret_cast<const bf16x8*>(&lB[col][g * 8]);
      bf16x8 bl = *reinterpret_cast<const bf16x8*>(&lB[col][32 + g * 8]);
      acc[j] = __builtin_amdgcn_mfma_f32_16x16x32_bf16(ahi, bh, acc[j], 0, 0, 0);
      acc[j] = __builtin_amdgcn_mfma_f32_16x16x32_bf16(alo, bh, acc[j], 0, 0, 0);
      acc[j] = __builtin_amdgcn_mfma_f32_16x16x32_bf16(ahi, bl, acc[j], 0, 0, 0);
    }
    __syncthreads();
  }

  // ---- epilogue: scale, softmax over 512 cols, dropout, write P bf16 ----
  const int rowbase = wr * 16 + g * 4;
  float mx[4] = {-3.4e38f, -3.4e38f, -3.4e38f, -3.4e38f};
#pragma unroll
  for (int j = 0; j < 8; ++j)
#pragma unroll
    for (int r = 0; r < 4; ++r) {
      acc[j][r] *= SM_SCALE;
      mx[r] = fmaxf(mx[r], acc[j][r]);
    }
#pragma unroll
  for (int s = 1; s < 16; s <<= 1)
#pragma unroll
    for (int r = 0; r < 4; ++r) mx[r] = fmaxf(mx[r], __shfl_xor(mx[r], s, 64));
  if (c16 == 0) {
#pragma unroll
    for (int r = 0; r < 4; ++r) redm[wc][rowbase + r] = mx[r];
  }
  __syncthreads();
  float rmax[4], sum[4] = {0.f, 0.f, 0.f, 0.f};
#pragma unroll
  for (int r = 0; r < 4; ++r)
    rmax[r] = fmaxf(fmaxf(redm[0][rowbase + r], redm[1][rowbase + r]),
                    fmaxf(redm[2][rowbase + r], redm[3][rowbase + r]));
#pragma unroll
  for (int j = 0; j < 8; ++j)
#pragma unroll
    for (int r = 0; r < 4; ++r) {
      float e = expf(acc[j][r] - rmax[r]);
      acc[j][r] = e;
      sum[r] += e;
    }
#pragma unroll
  for (int s = 1; s < 16; s <<= 1)
#pragma unroll
    for (int r = 0; r < 4; ++r) sum[r] += __shfl_xor(sum[r], s, 64);
  if (c16 == 0) {
#pragma unroll
    for (int r = 0; r < 4; ++r) reds[wc][rowbase + r] = sum[r];
  }
  __syncthreads();
  float scl[4];
#pragma unroll
  for (int r = 0; r < 4; ++r)
    scl[r] = DROP_SCALE / (reds[0][rowbase + r] + reds[1][rowbase + r] +
                           reds[2][rowbase + r] + reds[3][rowbase + r]);

#pragma unroll
  for (int j = 0; j < 8; ++j) {
    const int col = wc * 128 + j * 16 + c16;
#pragma unroll
    for (int r = 0; r < 4; ++r) {
      uint32_t idx = (uint32_t)(brow + rowbase + r) * 512u + (uint32_t)col;
      float pv = drop_keep(idx) ? acc[j][r] * scl[r] : 0.0f;
      P[idx] = f2bf(pv);
    }
  }
}

// ---------- kernel 3: out = P[16384][512] @ vT[4096][512]^T (bf16 MFMA) ----------
// v4: 256x256 tile, BK=32, 512 thr (8 waves, 2x4; each wave 128x64 out).
// Reg-staged padded LDS [256][40] (80B stride -> <=2-way read conflicts).
// Read traffic halved vs 128^2: P x16 + vT x64 = 512 MB.
__global__ __launch_bounds__(512) void k_pv(const unsigned short* __restrict__ P,
                                            const unsigned short* __restrict__ VT,
                                            float* __restrict__ out) {
  __shared__ unsigned short lA[256][40];  // 20KB
  __shared__ unsigned short lB[256][40];  // 20KB
  const int tid = threadIdx.x;
  const int l = tid & 63, w = tid >> 6;
  const int wr = w >> 2, wc = w & 3;      // wave grid 2 x 4
  const int g = l >> 4, c16 = l & 15;

  // XCD-aware bijective swizzle (1024 % 8 == 0)
  const int bid = blockIdx.x;
  const int x = (bid & 7) * 128 + (bid >> 3);
  const int brow = (x >> 4) * 256;   // 64 row-panels
  const int bcol = (x & 15) * 256;   // 16 col-panels

  f32x4 acc[8][4] = {};

  for (int kt = 0; kt < 16; ++kt) {
    const int k0 = kt * 32;
    // stage P and vT tiles [256][32] each: 1024 chunks of 8 shorts per matrix
#pragma unroll
    for (int p = 0; p < 2; ++p) {
      int c = p * 512 + tid;
      int row = c >> 2, sub = c & 3;
      u16x8 va = *reinterpret_cast<const u16x8*>(
          P + (size_t)(brow + row) * 512 + k0 + sub * 8);
      u16x8 vb = *reinterpret_cast<const u16x8*>(
          VT + (size_t)(bcol + row) * 512 + k0 + sub * 8);
      *reinterpret_cast<u16x8*>(&lA[row][sub * 8]) = va;
      *reinterpret_cast<u16x8*>(&lB[row][sub * 8]) = vb;
    }
    __syncthreads();

    bf16x8 a[8], b[4];
#pragma unroll
    for (int i = 0; i < 8; ++i)
      a[i] = *reinterpret_cast<const bf16x8*>(&lA[wr * 128 + i * 16 + c16][g * 8]);
#pragma unroll
    for (int j = 0; j < 4; ++j)
      b[j] = *reinterpret_cast<const bf16x8*>(&lB[wc * 64 + j * 16 + c16][g * 8]);
#pragma unroll
    for (int i = 0; i < 8; ++i)
#pragma unroll
      for (int j = 0; j < 4; ++j)
        acc[i][j] = __builtin_amdgcn_mfma_f32_16x16x32_bf16(a[i], b[j], acc[i][j], 0, 0, 0);
    __syncthreads();
  }

  // C/D layout (validated r4): col = lane&15, row = (lane>>4)*4 + reg
#pragma unroll
  for (int i = 0; i < 8; ++i)
#pragma unroll
    for (int r = 0; r < 4; ++r) {
      const size_t row = (size_t)(brow + wr * 128 + i * 16 + g * 4 + r);
      float* o = out + row * 4096 + bcol + wc * 64 + c16;
#pragma unroll
      for (int j = 0; j < 4; ++j) o[j * 16] = acc[i][j][r];
    }
}

// ---------- launch ----------
extern "C" void kernel_launch(void* const* d_in, const int* in_sizes, int n_in,
                              void* d_out, int out_size, void* d_ws, size_t ws_size,
                              hipStream_t stream) {
  (void)in_sizes; (void)n_in; (void)out_size; (void)ws_size;
  const float* in1   = (const float*)d_in[0];   // [16384][512]
  const float* in2   = (const float*)d_in[1];   // [512][512]
  const float* value = (const float*)d_in[2];   // [512][4096]
  float* out = (float*)d_out;                   // [16384][4096]

  unsigned short* vT    = (unsigned short*)d_ws;  // 4 MB   [4096][512] bf16
  unsigned short* Pb    = vT + 2097152;           // 16 MB  [16384][512] bf16
  unsigned short* in2hi = Pb + 8388608;           // 0.5 MB [512][512] bf16
  unsigned short* in2lo = in2hi + 262144;         // 0.5 MB

  k_vt<<<dim3(128, 16), dim3(256), 0, stream>>>(value, vT);
  k_split<<<dim3(256), dim3(256), 0, stream>>>(in2, in2hi, in2lo, 65536);
  k_qk<<<dim3(512), dim3(512), 0, stream>>>(in1, in2hi, in2lo, Pb);
  k_pv<<<dim3(1024), dim3(512), 0, stream>>>(Pb, vT, out);
}

// Round 14
// 199.996 us; speedup vs baseline: 1.0810x; 1.0402x over previous
//
#include <hip/hip_runtime.h>
#include <stdint.h>

// r14: k_pv v5 = double-buffered 256x256/BK=64, early-issued global_load_lds
// (stage t+1 during t's MFMA), ONE barrier per K-tile, T2-style XOR slot
// swizzle (linear LDS dest + pre-swizzled source + swizzled ds_read), T5
// setprio. Theory: all five prior pv variants (119-134us) sat at the 2-phase
// structural ceiling (m233 ~607 TF); the sync skeleton is the invariant.
// qk/prep byte-identical to r11. Ledger: pv = dur - 81.5.

// ---------- types ----------
typedef __bf16 bf16x8 __attribute__((ext_vector_type(8)));
typedef unsigned short u16x8 __attribute__((ext_vector_type(8)));
typedef float f32x4 __attribute__((ext_vector_type(4)));

#define SM_SCALE 4.419417382415922e-02f /* 1/22.627416997969522 */
#define DROP_SCALE (1.0f / 0.9f)

// ---------- helpers ----------
__device__ __forceinline__ unsigned short f2bf(float f) {
  uint32_t u = __float_as_uint(f);
  uint32_t r = (u + 0x7FFFu + ((u >> 16) & 1u)) >> 16;  // RNE
  return (unsigned short)r;
}
__device__ __forceinline__ float bf2f(unsigned short h) {
  return __uint_as_float(((uint32_t)h) << 16);
}

// async global->LDS, 16B/lane. LDS dest = wave-uniform base + lane*16.
__device__ __forceinline__ void async16(const void* g, void* l) {
  __builtin_amdgcn_global_load_lds(
      (__attribute__((address_space(1))) uint32_t*)g,
      (__attribute__((address_space(3))) uint32_t*)l, 16, 0, 0);
}

// JAX threefry2x32 with key (0,42). [validated r4]
__device__ __forceinline__ void threefry2x32(uint32_t x0, uint32_t x1,
                                             uint32_t& o0, uint32_t& o1) {
  const uint32_t K0 = 0u, K1 = 42u;
  const uint32_t K2 = K0 ^ K1 ^ 0x1BD11BDAu;
  x0 += K0; x1 += K1;
#define TF_R(rot) { x0 += x1; x1 = (x1 << rot) | (x1 >> (32 - rot)); x1 ^= x0; }
  TF_R(13) TF_R(15) TF_R(26) TF_R(6)  x0 += K1; x1 += K2 + 1u;
  TF_R(17) TF_R(29) TF_R(16) TF_R(24) x0 += K2; x1 += K0 + 2u;
  TF_R(13) TF_R(15) TF_R(26) TF_R(6)  x0 += K0; x1 += K1 + 3u;
  TF_R(17) TF_R(29) TF_R(16) TF_R(24) x0 += K1; x1 += K2 + 4u;
  TF_R(13) TF_R(15) TF_R(26) TF_R(6)  x0 += K2; x1 += K0 + 5u;
#undef TF_R
  o0 = x0; o1 = x1;
}

// keep-mask, JAX partitionable threefry, ctr=(0,idx), XOR-fold. [validated r4]
__device__ __forceinline__ bool drop_keep(uint32_t idx) {
  uint32_t o0, o1;
  threefry2x32(0u, idx, o0, o1);
  uint32_t bits = o0 ^ o1;
  float u = __uint_as_float((bits >> 9) | 0x3f800000u) - 1.0f;  // [0,1)
  return u < 0.9f;
}

// ---------- kernel 1: value[512][4096] f32 -> valueT[4096][512] bf16 [validated r4] ----
__global__ __launch_bounds__(256) void k_vt(const float* __restrict__ v,
                                            unsigned short* __restrict__ vt) {
  __shared__ float tile[32][33];
  const int nb = blockIdx.x;   // 0..127
  const int kb = blockIdx.y;   // 0..15
  const int tx = threadIdx.x & 31, ty = threadIdx.x >> 5;  // 32 x 8
#pragma unroll
  for (int yy = 0; yy < 4; ++yy) {
    int row = ty + yy * 8;
    tile[row][tx] = v[(size_t)(kb * 32 + row) * 4096 + nb * 32 + tx];
  }
  __syncthreads();
#pragma unroll
  for (int yy = 0; yy < 4; ++yy) {
    int row = ty + yy * 8;
    vt[(size_t)(nb * 32 + row) * 512 + kb * 32 + tx] = f2bf(tile[tx][row]);
  }
}

// ---------- kernel 1b: in2 f32 -> bf16 hi/lo split [validated r5] ----------
__global__ __launch_bounds__(256) void k_split(const float* __restrict__ src,
                                               unsigned short* __restrict__ hi,
                                               unsigned short* __restrict__ lo,
                                               int n4) {
  int i = blockIdx.x * 256 + threadIdx.x;
  if (i >= n4) return;
  float4 v = reinterpret_cast<const float4*>(src)[i];
  ushort4 h, l;
  h.x = f2bf(v.x); l.x = f2bf(v.x - bf2f(h.x));
  h.y = f2bf(v.y); l.y = f2bf(v.y - bf2f(h.y));
  h.z = f2bf(v.z); l.z = f2bf(v.z - bf2f(h.z));
  h.w = f2bf(v.w); l.w = f2bf(v.w - bf2f(h.w));
  reinterpret_cast<ushort4*>(hi)[i] = h;
  reinterpret_cast<ushort4*>(lo)[i] = l;
}

// ---------- kernel 2: QK^T (split-bf16 MFMA) + softmax + dropout -> P bf16 ----------
// [v2 exact bytes — measured 76.5us]
__global__ __launch_bounds__(512) void k_qk(const float* __restrict__ in1,
                                            const unsigned short* __restrict__ B2hi,
                                            const unsigned short* __restrict__ B2lo,
                                            unsigned short* __restrict__ P) {
  __shared__ unsigned short lB[512][72];  // [col][hi 0..31 | lo 32..63 | pad] 73.7KB
  __shared__ float redm[4][32], reds[4][32];

  const int tid = threadIdx.x;
  const int l = tid & 63, w = tid >> 6;
  const int wr = w >> 2, wc = w & 3;      // wave grid 2 x 4
  const int g = l >> 4, c16 = l & 15;
  const int brow = blockIdx.x * 32;

  f32x4 acc[8] = {};

  for (int kt = 0; kt < 16; ++kt) {
    const int k0 = kt * 32;
    // ---- stage B hi+lo tile [512 cols][32 k] each ----
#pragma unroll
    for (int i = 0; i < 8; ++i) {
      int c = i * 512 + tid;                // 4096 chunks of 8 shorts
      int col = c >> 3, half = (c >> 2) & 1, sub = c & 3;
      const unsigned short* src = (half ? B2lo : B2hi) + (size_t)col * 512 + k0 + sub * 8;
      *reinterpret_cast<u16x8*>(&lB[col][half * 32 + sub * 8]) =
          *reinterpret_cast<const u16x8*>(src);
    }
    // ---- A fragment direct from global, split in-register ----
    const int arow = brow + wr * 16 + c16;
    float4 v0 = *reinterpret_cast<const float4*>(in1 + (size_t)arow * 512 + k0 + g * 8);
    float4 v1 = *reinterpret_cast<const float4*>(in1 + (size_t)arow * 512 + k0 + g * 8 + 4);
    bf16x8 ahi, alo;
    {
      float vv[8] = {v0.x, v0.y, v0.z, v0.w, v1.x, v1.y, v1.z, v1.w};
      unsigned short h[8], lo8[8];
#pragma unroll
      for (int e = 0; e < 8; ++e) {
        h[e] = f2bf(vv[e]);
        lo8[e] = f2bf(vv[e] - bf2f(h[e]));
      }
      ahi = *reinterpret_cast<const bf16x8*>(h);
      alo = *reinterpret_cast<const bf16x8*>(lo8);
    }
    __syncthreads();
#pragma unroll
    for (int j = 0; j < 8; ++j) {
      const int col = wc * 128 + j * 16 + c16;
      bf16x8 bh = *reinterpret_cast<const bf16x8*>(&lB[col][g * 8]);
      bf16x8 bl = *reinterpret_cast<const bf16x8*>(&lB[col][32 + g * 8]);
      acc[j] = __builtin_amdgcn_mfma_f32_16x16x32_bf16(ahi, bh, acc[j], 0, 0, 0);
      acc[j] = __builtin_amdgcn_mfma_f32_16x16x32_bf16(alo, bh, acc[j], 0, 0, 0);
      acc[j] = __builtin_amdgcn_mfma_f32_16x16x32_bf16(ahi, bl, acc[j], 0, 0, 0);
    }
    __syncthreads();
  }

  // ---- epilogue: scale, softmax over 512 cols, dropout, write P bf16 ----
  const int rowbase = wr * 16 + g * 4;
  float mx[4] = {-3.4e38f, -3.4e38f, -3.4e38f, -3.4e38f};
#pragma unroll
  for (int j = 0; j < 8; ++j)
#pragma unroll
    for (int r = 0; r < 4; ++r) {
      acc[j][r] *= SM_SCALE;
      mx[r] = fmaxf(mx[r], acc[j][r]);
    }
#pragma unroll
  for (int s = 1; s < 16; s <<= 1)
#pragma unroll
    for (int r = 0; r < 4; ++r) mx[r] = fmaxf(mx[r], __shfl_xor(mx[r], s, 64));
  if (c16 == 0) {
#pragma unroll
    for (int r = 0; r < 4; ++r) redm[wc][rowbase + r] = mx[r];
  }
  __syncthreads();
  float rmax[4], sum[4] = {0.f, 0.f, 0.f, 0.f};
#pragma unroll
  for (int r = 0; r < 4; ++r)
    rmax[r] = fmaxf(fmaxf(redm[0][rowbase + r], redm[1][rowbase + r]),
                    fmaxf(redm[2][rowbase + r], redm[3][rowbase + r]));
#pragma unroll
  for (int j = 0; j < 8; ++j)
#pragma unroll
    for (int r = 0; r < 4; ++r) {
      float e = expf(acc[j][r] - rmax[r]);
      acc[j][r] = e;
      sum[r] += e;
    }
#pragma unroll
  for (int s = 1; s < 16; s <<= 1)
#pragma unroll
    for (int r = 0; r < 4; ++r) sum[r] += __shfl_xor(sum[r], s, 64);
  if (c16 == 0) {
#pragma unroll
    for (int r = 0; r < 4; ++r) reds[wc][rowbase + r] = sum[r];
  }
  __syncthreads();
  float scl[4];
#pragma unroll
  for (int r = 0; r < 4; ++r)
    scl[r] = DROP_SCALE / (reds[0][rowbase + r] + reds[1][rowbase + r] +
                           reds[2][rowbase + r] + reds[3][rowbase + r]);

#pragma unroll
  for (int j = 0; j < 8; ++j) {
    const int col = wc * 128 + j * 16 + c16;
#pragma unroll
    for (int r = 0; r < 4; ++r) {
      uint32_t idx = (uint32_t)(brow + rowbase + r) * 512u + (uint32_t)col;
      float pv = drop_keep(idx) ? acc[j][r] * scl[r] : 0.0f;
      P[idx] = f2bf(pv);
    }
  }
}

// ---------- kernel 3: out = P[16384][512] @ vT[4096][512]^T (bf16 MFMA) ----------
// v5: 256x256, BK=64, 8 waves (2x4), double-buffered gload_lds, early-issue
// staging, 1 barrier/K-tile, XOR slot swizzle both-sides, setprio. 128KB LDS.
__global__ __launch_bounds__(512) void k_pv(const unsigned short* __restrict__ P,
                                            const unsigned short* __restrict__ VT,
                                            float* __restrict__ out) {
  __shared__ unsigned short lA[2][256 * 64];  // 2 x 32 KB
  __shared__ unsigned short lB[2][256 * 64];  // 2 x 32 KB
  const int tid = threadIdx.x;
  const int l = tid & 63, w = tid >> 6;
  const int wr = w >> 2, wc = w & 3;          // wave grid 2(M) x 4(N)
  const int g = l >> 4, c16 = l & 15;

  // XCD-aware bijective swizzle (1024 % 8 == 0)
  const int bid = blockIdx.x;
  const int x = (bid & 7) * 128 + (bid >> 3);
  const int brow = (x >> 4) * 256;   // 64 row-panels
  const int bcol = (x & 15) * 256;   // 16 col-panels

  // staging: round i (0..3) covers rows i*64 + w*8 + (l>>3), 16B slot l&7.
  // LDS dest linear; global source slot pre-swizzled: s ^ (row&7).
  const int srow = w * 8 + (l >> 3);            // row within 64-row round
  const int sslot = (l & 7) ^ (srow & 7);       // (i*64,w*8 are 0 mod 8)
  const unsigned short* baseA = P + (size_t)(brow + srow) * 512 + sslot * 8;
  const unsigned short* baseB = VT + (size_t)(bcol + srow) * 512 + sslot * 8;

  f32x4 acc[8][4] = {};

  // prologue: stage tile 0 -> buf 0
#pragma unroll
  for (int i = 0; i < 4; ++i) {
    async16(baseA + (size_t)i * 64 * 512, &lA[0][(i * 512 + w * 64) * 8]);
    async16(baseB + (size_t)i * 64 * 512, &lB[0][(i * 512 + w * 64) * 8]);
  }
  asm volatile("s_waitcnt vmcnt(0)" ::: "memory");
  __syncthreads();

  for (int kt = 0; kt < 8; ++kt) {
    const int cur = kt & 1;
    const int kn = (kt + 1) * 64;  // next tile's k offset
#pragma unroll
    for (int q = 0; q < 4; ++q) {      // quadrant phases: qm=q>>1, qn=q&1
      const int qm = q >> 1, qn = q & 1;
      if (kt < 7 && q < 2) {           // early-issue stage of tile kt+1
#pragma unroll
        for (int i2 = 0; i2 < 2; ++i2) {
          int i = q * 2 + i2;
          async16(baseA + (size_t)i * 64 * 512 + kn,
                  &lA[cur ^ 1][(i * 512 + w * 64) * 8]);
          async16(baseB + (size_t)i * 64 * 512 + kn,
                  &lB[cur ^ 1][(i * 512 + w * 64) * 8]);
        }
      }
      bf16x8 a[4][2], b[2][2];
#pragma unroll
      for (int mi = 0; mi < 4; ++mi) {
        int ar = wr * 128 + qm * 64 + mi * 16 + c16;
#pragma unroll
        for (int kh = 0; kh < 2; ++kh)
          a[mi][kh] = *reinterpret_cast<const bf16x8*>(
              &lA[cur][ar * 64 + (((kh << 2) | g) ^ (ar & 7)) * 8]);
      }
#pragma unroll
      for (int nj = 0; nj < 2; ++nj) {
        int br = wc * 64 + qn * 32 + nj * 16 + c16;
#pragma unroll
        for (int kh = 0; kh < 2; ++kh)
          b[nj][kh] = *reinterpret_cast<const bf16x8*>(
              &lB[cur][br * 64 + (((kh << 2) | g) ^ (br & 7)) * 8]);
      }
      __builtin_amdgcn_s_setprio(1);
#pragma unroll
      for (int mi = 0; mi < 4; ++mi)
#pragma unroll
        for (int nj = 0; nj < 2; ++nj)
#pragma unroll
          for (int kh = 0; kh < 2; ++kh)
            acc[qm * 4 + mi][qn * 2 + nj] = __builtin_amdgcn_mfma_f32_16x16x32_bf16(
                a[mi][kh], b[nj][kh], acc[qm * 4 + mi][qn * 2 + nj], 0, 0, 0);
      __builtin_amdgcn_s_setprio(0);
    }
    asm volatile("s_waitcnt vmcnt(0)" ::: "memory");
    __syncthreads();  // reads(cur) done block-wide; next tile's buffer complete
  }

  // C/D layout (validated r4): col = lane&15, row = (lane>>4)*4 + reg
  // rows: wr*128 + i*16 (i=0..7); cols: wc*64 + j*16 (j=0..3)
#pragma unroll
  for (int i = 0; i < 8; ++i)
#pragma unroll
    for (int r = 0; r < 4; ++r) {
      const size_t row = (size_t)(brow + wr * 128 + i * 16 + g * 4 + r);
      float* o = out + row * 4096 + bcol + wc * 64 + c16;
#pragma unroll
      for (int j = 0; j < 4; ++j) o[j * 16] = acc[i][j][r];
    }
}

// ---------- launch ----------
extern "C" void kernel_launch(void* const* d_in, const int* in_sizes, int n_in,
                              void* d_out, int out_size, void* d_ws, size_t ws_size,
                              hipStream_t stream) {
  (void)in_sizes; (void)n_in; (void)out_size; (void)ws_size;
  const float* in1   = (const float*)d_in[0];   // [16384][512]
  const float* in2   = (const float*)d_in[1];   // [512][512]
  const float* value = (const float*)d_in[2];   // [512][4096]
  float* out = (float*)d_out;                   // [16384][4096]

  unsigned short* vT    = (unsigned short*)d_ws;  // 4 MB   [4096][512] bf16
  unsigned short* Pb    = vT + 2097152;           // 16 MB  [16384][512] bf16
  unsigned short* in2hi = Pb + 8388608;           // 0.5 MB [512][512] bf16
  unsigned short* in2lo = in2hi + 262144;         // 0.5 MB

  k_vt<<<dim3(128, 16), dim3(256), 0, stream>>>(value, vT);
  k_split<<<dim3(256), dim3(256), 0, stream>>>(in2, in2hi, in2lo, 65536);
  k_qk<<<dim3(512), dim3(512), 0, stream>>>(in1, in2hi, in2lo, Pb);
  k_pv<<<dim3(1024), dim3(512), 0, stream>>>(Pb, vT, out);
}

// Round 15
// 186.469 us; speedup vs baseline: 1.1594x; 1.0725x over previous
//
#include <hip/hip_runtime.h>
#include <stdint.h>

// r15: k_pv v6 = counted-vmcnt deep pipeline (T3/T4 done right).
// k-half LDS regions [dbuf][kh][256x32] (128KB), 12 loads in flight,
// waits at vmcnt(8) (never 0 in steady state), 2 barriers/tile,
// 2-way-max read swizzle slot = g ^ ((row>>1)&3), setprio MFMA clusters.
// qk/prep byte-identical to r11. Ledger: pv = dur - 81.5.

// ---------- types ----------
typedef __bf16 bf16x8 __attribute__((ext_vector_type(8)));
typedef unsigned short u16x8 __attribute__((ext_vector_type(8)));
typedef float f32x4 __attribute__((ext_vector_type(4)));

#define SM_SCALE 4.419417382415922e-02f /* 1/22.627416997969522 */
#define DROP_SCALE (1.0f / 0.9f)

// ---------- helpers ----------
__device__ __forceinline__ unsigned short f2bf(float f) {
  uint32_t u = __float_as_uint(f);
  uint32_t r = (u + 0x7FFFu + ((u >> 16) & 1u)) >> 16;  // RNE
  return (unsigned short)r;
}
__device__ __forceinline__ float bf2f(unsigned short h) {
  return __uint_as_float(((uint32_t)h) << 16);
}

// async global->LDS, 16B/lane. LDS dest = wave-uniform base + lane*16.
__device__ __forceinline__ void async16(const void* g, void* l) {
  __builtin_amdgcn_global_load_lds(
      (__attribute__((address_space(1))) uint32_t*)g,
      (__attribute__((address_space(3))) uint32_t*)l, 16, 0, 0);
}

// JAX threefry2x32 with key (0,42). [validated r4]
__device__ __forceinline__ void threefry2x32(uint32_t x0, uint32_t x1,
                                             uint32_t& o0, uint32_t& o1) {
  const uint32_t K0 = 0u, K1 = 42u;
  const uint32_t K2 = K0 ^ K1 ^ 0x1BD11BDAu;
  x0 += K0; x1 += K1;
#define TF_R(rot) { x0 += x1; x1 = (x1 << rot) | (x1 >> (32 - rot)); x1 ^= x0; }
  TF_R(13) TF_R(15) TF_R(26) TF_R(6)  x0 += K1; x1 += K2 + 1u;
  TF_R(17) TF_R(29) TF_R(16) TF_R(24) x0 += K2; x1 += K0 + 2u;
  TF_R(13) TF_R(15) TF_R(26) TF_R(6)  x0 += K0; x1 += K1 + 3u;
  TF_R(17) TF_R(29) TF_R(16) TF_R(24) x0 += K1; x1 += K2 + 4u;
  TF_R(13) TF_R(15) TF_R(26) TF_R(6)  x0 += K2; x1 += K0 + 5u;
#undef TF_R
  o0 = x0; o1 = x1;
}

// keep-mask, JAX partitionable threefry, ctr=(0,idx), XOR-fold. [validated r4]
__device__ __forceinline__ bool drop_keep(uint32_t idx) {
  uint32_t o0, o1;
  threefry2x32(0u, idx, o0, o1);
  uint32_t bits = o0 ^ o1;
  float u = __uint_as_float((bits >> 9) | 0x3f800000u) - 1.0f;  // [0,1)
  return u < 0.9f;
}

// ---------- kernel 1: value[512][4096] f32 -> valueT[4096][512] bf16 [validated r4] ----
__global__ __launch_bounds__(256) void k_vt(const float* __restrict__ v,
                                            unsigned short* __restrict__ vt) {
  __shared__ float tile[32][33];
  const int nb = blockIdx.x;   // 0..127
  const int kb = blockIdx.y;   // 0..15
  const int tx = threadIdx.x & 31, ty = threadIdx.x >> 5;  // 32 x 8
#pragma unroll
  for (int yy = 0; yy < 4; ++yy) {
    int row = ty + yy * 8;
    tile[row][tx] = v[(size_t)(kb * 32 + row) * 4096 + nb * 32 + tx];
  }
  __syncthreads();
#pragma unroll
  for (int yy = 0; yy < 4; ++yy) {
    int row = ty + yy * 8;
    vt[(size_t)(nb * 32 + row) * 512 + kb * 32 + tx] = f2bf(tile[tx][row]);
  }
}

// ---------- kernel 1b: in2 f32 -> bf16 hi/lo split [validated r5] ----------
__global__ __launch_bounds__(256) void k_split(const float* __restrict__ src,
                                               unsigned short* __restrict__ hi,
                                               unsigned short* __restrict__ lo,
                                               int n4) {
  int i = blockIdx.x * 256 + threadIdx.x;
  if (i >= n4) return;
  float4 v = reinterpret_cast<const float4*>(src)[i];
  ushort4 h, l;
  h.x = f2bf(v.x); l.x = f2bf(v.x - bf2f(h.x));
  h.y = f2bf(v.y); l.y = f2bf(v.y - bf2f(h.y));
  h.z = f2bf(v.z); l.z = f2bf(v.z - bf2f(h.z));
  h.w = f2bf(v.w); l.w = f2bf(v.w - bf2f(h.w));
  reinterpret_cast<ushort4*>(hi)[i] = h;
  reinterpret_cast<ushort4*>(lo)[i] = l;
}

// ---------- kernel 2: QK^T (split-bf16 MFMA) + softmax + dropout -> P bf16 ----------
// [v2 exact bytes — measured 76.5us]
__global__ __launch_bounds__(512) void k_qk(const float* __restrict__ in1,
                                            const unsigned short* __restrict__ B2hi,
                                            const unsigned short* __restrict__ B2lo,
                                            unsigned short* __restrict__ P) {
  __shared__ unsigned short lB[512][72];  // [col][hi 0..31 | lo 32..63 | pad] 73.7KB
  __shared__ float redm[4][32], reds[4][32];

  const int tid = threadIdx.x;
  const int l = tid & 63, w = tid >> 6;
  const int wr = w >> 2, wc = w & 3;      // wave grid 2 x 4
  const int g = l >> 4, c16 = l & 15;
  const int brow = blockIdx.x * 32;

  f32x4 acc[8] = {};

  for (int kt = 0; kt < 16; ++kt) {
    const int k0 = kt * 32;
    // ---- stage B hi+lo tile [512 cols][32 k] each ----
#pragma unroll
    for (int i = 0; i < 8; ++i) {
      int c = i * 512 + tid;                // 4096 chunks of 8 shorts
      int col = c >> 3, half = (c >> 2) & 1, sub = c & 3;
      const unsigned short* src = (half ? B2lo : B2hi) + (size_t)col * 512 + k0 + sub * 8;
      *reinterpret_cast<u16x8*>(&lB[col][half * 32 + sub * 8]) =
          *reinterpret_cast<const u16x8*>(src);
    }
    // ---- A fragment direct from global, split in-register ----
    const int arow = brow + wr * 16 + c16;
    float4 v0 = *reinterpret_cast<const float4*>(in1 + (size_t)arow * 512 + k0 + g * 8);
    float4 v1 = *reinterpret_cast<const float4*>(in1 + (size_t)arow * 512 + k0 + g * 8 + 4);
    bf16x8 ahi, alo;
    {
      float vv[8] = {v0.x, v0.y, v0.z, v0.w, v1.x, v1.y, v1.z, v1.w};
      unsigned short h[8], lo8[8];
#pragma unroll
      for (int e = 0; e < 8; ++e) {
        h[e] = f2bf(vv[e]);
        lo8[e] = f2bf(vv[e] - bf2f(h[e]));
      }
      ahi = *reinterpret_cast<const bf16x8*>(h);
      alo = *reinterpret_cast<const bf16x8*>(lo8);
    }
    __syncthreads();
#pragma unroll
    for (int j = 0; j < 8; ++j) {
      const int col = wc * 128 + j * 16 + c16;
      bf16x8 bh = *reinterpret_cast<const bf16x8*>(&lB[col][g * 8]);
      bf16x8 bl = *reinterpret_cast<const bf16x8*>(&lB[col][32 + g * 8]);
      acc[j] = __builtin_amdgcn_mfma_f32_16x16x32_bf16(ahi, bh, acc[j], 0, 0, 0);
      acc[j] = __builtin_amdgcn_mfma_f32_16x16x32_bf16(alo, bh, acc[j], 0, 0, 0);
      acc[j] = __builtin_amdgcn_mfma_f32_16x16x32_bf16(ahi, bl, acc[j], 0, 0, 0);
    }
    __syncthreads();
  }

  // ---- epilogue: scale, softmax over 512 cols, dropout, write P bf16 ----
  const int rowbase = wr * 16 + g * 4;
  float mx[4] = {-3.4e38f, -3.4e38f, -3.4e38f, -3.4e38f};
#pragma unroll
  for (int j = 0; j < 8; ++j)
#pragma unroll
    for (int r = 0; r < 4; ++r) {
      acc[j][r] *= SM_SCALE;
      mx[r] = fmaxf(mx[r], acc[j][r]);
    }
#pragma unroll
  for (int s = 1; s < 16; s <<= 1)
#pragma unroll
    for (int r = 0; r < 4; ++r) mx[r] = fmaxf(mx[r], __shfl_xor(mx[r], s, 64));
  if (c16 == 0) {
#pragma unroll
    for (int r = 0; r < 4; ++r) redm[wc][rowbase + r] = mx[r];
  }
  __syncthreads();
  float rmax[4], sum[4] = {0.f, 0.f, 0.f, 0.f};
#pragma unroll
  for (int r = 0; r < 4; ++r)
    rmax[r] = fmaxf(fmaxf(redm[0][rowbase + r], redm[1][rowbase + r]),
                    fmaxf(redm[2][rowbase + r], redm[3][rowbase + r]));
#pragma unroll
  for (int j = 0; j < 8; ++j)
#pragma unroll
    for (int r = 0; r < 4; ++r) {
      float e = expf(acc[j][r] - rmax[r]);
      acc[j][r] = e;
      sum[r] += e;
    }
#pragma unroll
  for (int s = 1; s < 16; s <<= 1)
#pragma unroll
    for (int r = 0; r < 4; ++r) sum[r] += __shfl_xor(sum[r], s, 64);
  if (c16 == 0) {
#pragma unroll
    for (int r = 0; r < 4; ++r) reds[wc][rowbase + r] = sum[r];
  }
  __syncthreads();
  float scl[4];
#pragma unroll
  for (int r = 0; r < 4; ++r)
    scl[r] = DROP_SCALE / (reds[0][rowbase + r] + reds[1][rowbase + r] +
                           reds[2][rowbase + r] + reds[3][rowbase + r]);

#pragma unroll
  for (int j = 0; j < 8; ++j) {
    const int col = wc * 128 + j * 16 + c16;
#pragma unroll
    for (int r = 0; r < 4; ++r) {
      uint32_t idx = (uint32_t)(brow + rowbase + r) * 512u + (uint32_t)col;
      float pv = drop_keep(idx) ? acc[j][r] * scl[r] : 0.0f;
      P[idx] = f2bf(pv);
    }
  }
}

// ---------- kernel 3: out = P[16384][512] @ vT[4096][512]^T (bf16 MFMA) ----------
// v6: 256x256, BK=64 as two k-halves, counted-vmcnt pipeline.
// LDS 128KB: A regions [buf][kh][256 rows x 32k], B at +32768 shorts.
// Steady state: 12 loads in flight/wave, waits at vmcnt(8); 2 barriers/tile.
__global__ __launch_bounds__(512) void k_pv(const unsigned short* __restrict__ P,
                                            const unsigned short* __restrict__ VT,
                                            float* __restrict__ out) {
  __shared__ unsigned short lds[65536];  // 128 KB
  const int tid = threadIdx.x;
  const int l = tid & 63, w = tid >> 6;
  const int wr = w >> 2, wc = w & 3;     // wave grid 2(M) x 4(N)
  const int g = l >> 4, c16 = l & 15;

  // XCD-aware bijective swizzle (1024 % 8 == 0)
  const int bid = blockIdx.x;
  const int x = (bid & 7) * 128 + (bid >> 3);
  const int brow = (x >> 4) * 256;   // 64 row-panels
  const int bcol = (x & 15) * 256;   // 16 col-panels

  // staging geometry: unit i covers local rows i*128 + w*16 + (l>>2), slot p=l&3.
  // source slot pre-swizzled gs = p ^ ((lr>>1)&3): permutes within one 64B line
  // per 4-lane group (coalescing-safe); read side applies the same involution.
  const int lr_base = w * 16 + (l >> 2);
  const int p = l & 3;

  f32x4 acc[8][4] = {};

#define STAGE(t, kh, b)                                                        \
  {                                                                            \
    const int kofs = (t) * 64 + (kh) * 32;                                     \
    _Pragma("unroll")                                                          \
    for (int i = 0; i < 2; ++i) {                                              \
      int lr = i * 128 + lr_base;                                              \
      int gs = p ^ ((lr >> 1) & 3);                                            \
      unsigned short* dA = lds + ((b) * 2 + (kh)) * 8192 + (i * 512 + w * 64) * 8; \
      async16(P + (size_t)(brow + lr) * 512 + kofs + gs * 8, dA);              \
      async16(VT + (size_t)(bcol + lr) * 512 + kofs + gs * 8, dA + 32768);     \
    }                                                                          \
  }

#define FRAGS(b, kh)                                                           \
  const unsigned short* rbase = lds + ((b) * 2 + (kh)) * 8192;                 \
  bf16x8 a[8], bb[4];                                                          \
  _Pragma("unroll")                                                            \
  for (int mi = 0; mi < 8; ++mi) {                                             \
    int ar = wr * 128 + mi * 16 + c16;                                         \
    a[mi] = *reinterpret_cast<const bf16x8*>(rbase + ar * 32 +                 \
                                             (g ^ ((ar >> 1) & 3)) * 8);       \
  }                                                                            \
  _Pragma("unroll")                                                            \
  for (int nj = 0; nj < 4; ++nj) {                                             \
    int br = wc * 64 + nj * 16 + c16;                                          \
    bb[nj] = *reinterpret_cast<const bf16x8*>(rbase + 32768 + br * 32 +        \
                                              (g ^ ((br >> 1) & 3)) * 8);      \
  }

#define MFMA32()                                                               \
  __builtin_amdgcn_s_setprio(1);                                               \
  _Pragma("unroll")                                                            \
  for (int mi = 0; mi < 8; ++mi)                                               \
    _Pragma("unroll")                                                          \
    for (int nj = 0; nj < 4; ++nj)                                             \
      acc[mi][nj] = __builtin_amdgcn_mfma_f32_16x16x32_bf16(a[mi], bb[nj],     \
                                                            acc[mi][nj], 0, 0, 0); \
  __builtin_amdgcn_s_setprio(0);

  // prologue: 12 loads in flight (t0 kh0, t0 kh1, t1 kh0)
  STAGE(0, 0, 0) STAGE(0, 1, 0) STAGE(1, 0, 1)

  for (int t = 0; t < 7; ++t) {
    const int cur = t & 1, nxt = cur ^ 1;
    asm volatile("s_waitcnt vmcnt(8)" ::: "memory");   // t kh0 staged
    __builtin_amdgcn_s_barrier();
    STAGE(t + 1, 1, nxt)                               // -> 12 in flight
    {
      FRAGS(cur, 0)
      MFMA32()
    }
    asm volatile("s_waitcnt vmcnt(8)" ::: "memory");   // t kh1 staged
    __builtin_amdgcn_s_barrier();                      // + kh0 reads done
    if (t < 6) STAGE(t + 2, 0, cur)                    // kh0 region reusable
    {
      FRAGS(cur, 1)
      MFMA32()
    }
  }
  // tail t=7 (cur=1): 8 outstanding
  asm volatile("s_waitcnt vmcnt(4)" ::: "memory");
  __builtin_amdgcn_s_barrier();
  {
    FRAGS(1, 0)
    MFMA32()
  }
  asm volatile("s_waitcnt vmcnt(0)" ::: "memory");
  __builtin_amdgcn_s_barrier();
  {
    FRAGS(1, 1)
    MFMA32()
  }
#undef STAGE
#undef FRAGS
#undef MFMA32

  // C/D layout (validated r4): col = lane&15, row = (lane>>4)*4 + reg
#pragma unroll
  for (int i = 0; i < 8; ++i)
#pragma unroll
    for (int r = 0; r < 4; ++r) {
      const size_t row = (size_t)(brow + wr * 128 + i * 16 + g * 4 + r);
      float* o = out + row * 4096 + bcol + wc * 64 + c16;
#pragma unroll
      for (int j = 0; j < 4; ++j) o[j * 16] = acc[i][j][r];
    }
}

// ---------- launch ----------
extern "C" void kernel_launch(void* const* d_in, const int* in_sizes, int n_in,
                              void* d_out, int out_size, void* d_ws, size_t ws_size,
                              hipStream_t stream) {
  (void)in_sizes; (void)n_in; (void)out_size; (void)ws_size;
  const float* in1   = (const float*)d_in[0];   // [16384][512]
  const float* in2   = (const float*)d_in[1];   // [512][512]
  const float* value = (const float*)d_in[2];   // [512][4096]
  float* out = (float*)d_out;                   // [16384][4096]

  unsigned short* vT    = (unsigned short*)d_ws;  // 4 MB   [4096][512] bf16
  unsigned short* Pb    = vT + 2097152;           // 16 MB  [16384][512] bf16
  unsigned short* in2hi = Pb + 8388608;           // 0.5 MB [512][512] bf16
  unsigned short* in2lo = in2hi + 262144;         // 0.5 MB

  k_vt<<<dim3(128, 16), dim3(256), 0, stream>>>(value, vT);
  k_split<<<dim3(256), dim3(256), 0, stream>>>(in2, in2hi, in2lo, 65536);
  k_qk<<<dim3(512), dim3(512), 0, stream>>>(in1, in2hi, in2lo, Pb);
  k_pv<<<dim3(1024), dim3(512), 0, stream>>>(Pb, vT, out);
}

// Round 16
// 168.474 us; speedup vs baseline: 1.2832x; 1.1068x over previous
//
#include <hip/hip_runtime.h>
#include <stdint.h>

// r16: qk v7 = 64-row blocks (256 grid) + 2-term split (B-lo dropped, r9-validated)
// + __launch_bounds__(512,4) -> VGPR<=128, 2 blocks/CU (the lever r8 missed).
// B-staging 1GB -> 256MB; LDS 37KB conflict-free. pv v6 + prep byte-identical
// to r15. Ledger: qk = dur - 110 (pv 105 + prep 5).

// ---------- types ----------
typedef __bf16 bf16x8 __attribute__((ext_vector_type(8)));
typedef unsigned short u16x8 __attribute__((ext_vector_type(8)));
typedef float f32x4 __attribute__((ext_vector_type(4)));

#define SM_SCALE 4.419417382415922e-02f /* 1/22.627416997969522 */
#define DROP_SCALE (1.0f / 0.9f)

// ---------- helpers ----------
__device__ __forceinline__ unsigned short f2bf(float f) {
  uint32_t u = __float_as_uint(f);
  uint32_t r = (u + 0x7FFFu + ((u >> 16) & 1u)) >> 16;  // RNE
  return (unsigned short)r;
}
__device__ __forceinline__ float bf2f(unsigned short h) {
  return __uint_as_float(((uint32_t)h) << 16);
}

// async global->LDS, 16B/lane. LDS dest = wave-uniform base + lane*16.
__device__ __forceinline__ void async16(const void* g, void* l) {
  __builtin_amdgcn_global_load_lds(
      (__attribute__((address_space(1))) uint32_t*)g,
      (__attribute__((address_space(3))) uint32_t*)l, 16, 0, 0);
}

// JAX threefry2x32 with key (0,42). [validated r4]
__device__ __forceinline__ void threefry2x32(uint32_t x0, uint32_t x1,
                                             uint32_t& o0, uint32_t& o1) {
  const uint32_t K0 = 0u, K1 = 42u;
  const uint32_t K2 = K0 ^ K1 ^ 0x1BD11BDAu;
  x0 += K0; x1 += K1;
#define TF_R(rot) { x0 += x1; x1 = (x1 << rot) | (x1 >> (32 - rot)); x1 ^= x0; }
  TF_R(13) TF_R(15) TF_R(26) TF_R(6)  x0 += K1; x1 += K2 + 1u;
  TF_R(17) TF_R(29) TF_R(16) TF_R(24) x0 += K2; x1 += K0 + 2u;
  TF_R(13) TF_R(15) TF_R(26) TF_R(6)  x0 += K0; x1 += K1 + 3u;
  TF_R(17) TF_R(29) TF_R(16) TF_R(24) x0 += K1; x1 += K2 + 4u;
  TF_R(13) TF_R(15) TF_R(26) TF_R(6)  x0 += K2; x1 += K0 + 5u;
#undef TF_R
  o0 = x0; o1 = x1;
}

// keep-mask, JAX partitionable threefry, ctr=(0,idx), XOR-fold. [validated r4]
__device__ __forceinline__ bool drop_keep(uint32_t idx) {
  uint32_t o0, o1;
  threefry2x32(0u, idx, o0, o1);
  uint32_t bits = o0 ^ o1;
  float u = __uint_as_float((bits >> 9) | 0x3f800000u) - 1.0f;  // [0,1)
  return u < 0.9f;
}

// ---------- kernel 1: value[512][4096] f32 -> valueT[4096][512] bf16 [validated r4] ----
__global__ __launch_bounds__(256) void k_vt(const float* __restrict__ v,
                                            unsigned short* __restrict__ vt) {
  __shared__ float tile[32][33];
  const int nb = blockIdx.x;   // 0..127
  const int kb = blockIdx.y;   // 0..15
  const int tx = threadIdx.x & 31, ty = threadIdx.x >> 5;  // 32 x 8
#pragma unroll
  for (int yy = 0; yy < 4; ++yy) {
    int row = ty + yy * 8;
    tile[row][tx] = v[(size_t)(kb * 32 + row) * 4096 + nb * 32 + tx];
  }
  __syncthreads();
#pragma unroll
  for (int yy = 0; yy < 4; ++yy) {
    int row = ty + yy * 8;
    vt[(size_t)(nb * 32 + row) * 512 + kb * 32 + tx] = f2bf(tile[tx][row]);
  }
}

// ---------- kernel 1b: in2 f32 -> bf16 (RNE) [validated r9] ----------
__global__ __launch_bounds__(256) void k_cast(const float* __restrict__ src,
                                              unsigned short* __restrict__ dst,
                                              int n4) {
  int i = blockIdx.x * 256 + threadIdx.x;
  if (i >= n4) return;
  float4 v = reinterpret_cast<const float4*>(src)[i];
  ushort4 h;
  h.x = f2bf(v.x); h.y = f2bf(v.y); h.z = f2bf(v.z); h.w = f2bf(v.w);
  reinterpret_cast<ushort4*>(dst)[i] = h;
}

// ---------- kernel 2: QK^T (A-split bf16 MFMA, 2-term) + softmax + dropout -> P ----
// v7: 256 blocks x 512 thr (8 waves, 4 row-groups x 2 col-halves), 64 rows/block.
// B staged once per K-tile (bf16 hi only; 2-term validated r9). LDS 37KB,
// 72B stride -> conflict-free 16-lane ds_read. launch_bounds(512,4) -> 2 blocks/CU.
__global__ __launch_bounds__(512, 4) void k_qk(const float* __restrict__ in1,
                                               const unsigned short* __restrict__ B2,
                                               unsigned short* __restrict__ P) {
  __shared__ unsigned short lB[512][36];  // 36.9KB
  __shared__ float redm[2][64], reds[2][64];

  const int tid = threadIdx.x;
  const int l = tid & 63, w = tid >> 6;
  const int wr = w >> 1, wc = w & 1;      // wave grid 4 x 2
  const int g = l >> 4, c16 = l & 15;
  const int brow = blockIdx.x * 64;

  f32x4 acc[16] = {};

  for (int kt = 0; kt < 16; ++kt) {
    const int k0 = kt * 32;
    // ---- stage B tile [512 cols][32 k] (bf16) ----
#pragma unroll
    for (int i = 0; i < 4; ++i) {
      int c = i * 512 + tid;                // 2048 chunks of 8 shorts
      int col = c >> 2, sub = c & 3;
      *reinterpret_cast<u16x8*>(&lB[col][sub * 8]) =
          *reinterpret_cast<const u16x8*>(B2 + (size_t)col * 512 + k0 + sub * 8);
    }
    // ---- A fragment direct from global, split in-register [r6-validated] ----
    const int arow = brow + wr * 16 + c16;
    float4 v0 = *reinterpret_cast<const float4*>(in1 + (size_t)arow * 512 + k0 + g * 8);
    float4 v1 = *reinterpret_cast<const float4*>(in1 + (size_t)arow * 512 + k0 + g * 8 + 4);
    bf16x8 ahi, alo;
    {
      float vv[8] = {v0.x, v0.y, v0.z, v0.w, v1.x, v1.y, v1.z, v1.w};
      unsigned short h[8], lo8[8];
#pragma unroll
      for (int e = 0; e < 8; ++e) {
        h[e] = f2bf(vv[e]);
        lo8[e] = f2bf(vv[e] - bf2f(h[e]));
      }
      ahi = *reinterpret_cast<const bf16x8*>(h);
      alo = *reinterpret_cast<const bf16x8*>(lo8);
    }
    __syncthreads();
#pragma unroll
    for (int j = 0; j < 16; ++j) {
      const int col = wc * 256 + j * 16 + c16;
      bf16x8 bh = *reinterpret_cast<const bf16x8*>(&lB[col][g * 8]);
      acc[j] = __builtin_amdgcn_mfma_f32_16x16x32_bf16(ahi, bh, acc[j], 0, 0, 0);
      acc[j] = __builtin_amdgcn_mfma_f32_16x16x32_bf16(alo, bh, acc[j], 0, 0, 0);
    }
    __syncthreads();
  }

  // ---- epilogue: scale, softmax over 512 cols, dropout, write P bf16 [r8-validated] ----
  // C/D layout: col = c16 (+j*16+wc*256), row = g*4 + r (+wr*16)
  const int rowbase = wr * 16 + g * 4;
  float mx[4] = {-3.4e38f, -3.4e38f, -3.4e38f, -3.4e38f};
#pragma unroll
  for (int j = 0; j < 16; ++j)
#pragma unroll
    for (int r = 0; r < 4; ++r) {
      acc[j][r] *= SM_SCALE;
      mx[r] = fmaxf(mx[r], acc[j][r]);
    }
#pragma unroll
  for (int s = 1; s < 16; s <<= 1)
#pragma unroll
    for (int r = 0; r < 4; ++r) mx[r] = fmaxf(mx[r], __shfl_xor(mx[r], s, 64));
  if (c16 == 0) {
#pragma unroll
    for (int r = 0; r < 4; ++r) redm[wc][rowbase + r] = mx[r];
  }
  __syncthreads();
  float rmax[4], sum[4] = {0.f, 0.f, 0.f, 0.f};
#pragma unroll
  for (int r = 0; r < 4; ++r)
    rmax[r] = fmaxf(redm[0][rowbase + r], redm[1][rowbase + r]);
#pragma unroll
  for (int j = 0; j < 16; ++j)
#pragma unroll
    for (int r = 0; r < 4; ++r) {
      float e = expf(acc[j][r] - rmax[r]);
      acc[j][r] = e;
      sum[r] += e;
    }
#pragma unroll
  for (int s = 1; s < 16; s <<= 1)
#pragma unroll
    for (int r = 0; r < 4; ++r) sum[r] += __shfl_xor(sum[r], s, 64);
  if (c16 == 0) {
#pragma unroll
    for (int r = 0; r < 4; ++r) reds[wc][rowbase + r] = sum[r];
  }
  __syncthreads();
  float scl[4];
#pragma unroll
  for (int r = 0; r < 4; ++r)
    scl[r] = DROP_SCALE / (reds[0][rowbase + r] + reds[1][rowbase + r]);

#pragma unroll
  for (int j = 0; j < 16; ++j) {
    const int col = wc * 256 + j * 16 + c16;
#pragma unroll
    for (int r = 0; r < 4; ++r) {
      uint32_t idx = (uint32_t)(brow + rowbase + r) * 512u + (uint32_t)col;
      float pv = drop_keep(idx) ? acc[j][r] * scl[r] : 0.0f;
      P[idx] = f2bf(pv);
    }
  }
}

// ---------- kernel 3: out = P[16384][512] @ vT[4096][512]^T (bf16 MFMA) ----------
// [v6 exact bytes — r15, counted-vmcnt pipeline, ~105us]
__global__ __launch_bounds__(512) void k_pv(const unsigned short* __restrict__ P,
                                            const unsigned short* __restrict__ VT,
                                            float* __restrict__ out) {
  __shared__ unsigned short lds[65536];  // 128 KB
  const int tid = threadIdx.x;
  const int l = tid & 63, w = tid >> 6;
  const int wr = w >> 2, wc = w & 3;     // wave grid 2(M) x 4(N)
  const int g = l >> 4, c16 = l & 15;

  const int bid = blockIdx.x;
  const int x = (bid & 7) * 128 + (bid >> 3);
  const int brow = (x >> 4) * 256;   // 64 row-panels
  const int bcol = (x & 15) * 256;   // 16 col-panels

  const int lr_base = w * 16 + (l >> 2);
  const int p = l & 3;

  f32x4 acc[8][4] = {};

#define STAGE(t, kh, b)                                                        \
  {                                                                            \
    const int kofs = (t) * 64 + (kh) * 32;                                     \
    _Pragma("unroll")                                                          \
    for (int i = 0; i < 2; ++i) {                                              \
      int lr = i * 128 + lr_base;                                              \
      int gs = p ^ ((lr >> 1) & 3);                                            \
      unsigned short* dA = lds + ((b) * 2 + (kh)) * 8192 + (i * 512 + w * 64) * 8; \
      async16(P + (size_t)(brow + lr) * 512 + kofs + gs * 8, dA);              \
      async16(VT + (size_t)(bcol + lr) * 512 + kofs + gs * 8, dA + 32768);     \
    }                                                                          \
  }

#define FRAGS(b, kh)                                                           \
  const unsigned short* rbase = lds + ((b) * 2 + (kh)) * 8192;                 \
  bf16x8 a[8], bb[4];                                                          \
  _Pragma("unroll")                                                            \
  for (int mi = 0; mi < 8; ++mi) {                                             \
    int ar = wr * 128 + mi * 16 + c16;                                         \
    a[mi] = *reinterpret_cast<const bf16x8*>(rbase + ar * 32 +                 \
                                             (g ^ ((ar >> 1) & 3)) * 8);       \
  }                                                                            \
  _Pragma("unroll")                                                            \
  for (int nj = 0; nj < 4; ++nj) {                                             \
    int br = wc * 64 + nj * 16 + c16;                                          \
    bb[nj] = *reinterpret_cast<const bf16x8*>(rbase + 32768 + br * 32 +        \
                                              (g ^ ((br >> 1) & 3)) * 8);      \
  }

#define MFMA32()                                                               \
  __builtin_amdgcn_s_setprio(1);                                               \
  _Pragma("unroll")                                                            \
  for (int mi = 0; mi < 8; ++mi)                                               \
    _Pragma("unroll")                                                          \
    for (int nj = 0; nj < 4; ++nj)                                             \
      acc[mi][nj] = __builtin_amdgcn_mfma_f32_16x16x32_bf16(a[mi], bb[nj],     \
                                                            acc[mi][nj], 0, 0, 0); \
  __builtin_amdgcn_s_setprio(0);

  STAGE(0, 0, 0) STAGE(0, 1, 0) STAGE(1, 0, 1)

  for (int t = 0; t < 7; ++t) {
    const int cur = t & 1, nxt = cur ^ 1;
    asm volatile("s_waitcnt vmcnt(8)" ::: "memory");
    __builtin_amdgcn_s_barrier();
    STAGE(t + 1, 1, nxt)
    {
      FRAGS(cur, 0)
      MFMA32()
    }
    asm volatile("s_waitcnt vmcnt(8)" ::: "memory");
    __builtin_amdgcn_s_barrier();
    if (t < 6) STAGE(t + 2, 0, cur)
    {
      FRAGS(cur, 1)
      MFMA32()
    }
  }
  asm volatile("s_waitcnt vmcnt(4)" ::: "memory");
  __builtin_amdgcn_s_barrier();
  {
    FRAGS(1, 0)
    MFMA32()
  }
  asm volatile("s_waitcnt vmcnt(0)" ::: "memory");
  __builtin_amdgcn_s_barrier();
  {
    FRAGS(1, 1)
    MFMA32()
  }
#undef STAGE
#undef FRAGS
#undef MFMA32

  // C/D layout (validated r4): col = lane&15, row = (lane>>4)*4 + reg
#pragma unroll
  for (int i = 0; i < 8; ++i)
#pragma unroll
    for (int r = 0; r < 4; ++r) {
      const size_t row = (size_t)(brow + wr * 128 + i * 16 + g * 4 + r);
      float* o = out + row * 4096 + bcol + wc * 64 + c16;
#pragma unroll
      for (int j = 0; j < 4; ++j) o[j * 16] = acc[i][j][r];
    }
}

// ---------- launch ----------
extern "C" void kernel_launch(void* const* d_in, const int* in_sizes, int n_in,
                              void* d_out, int out_size, void* d_ws, size_t ws_size,
                              hipStream_t stream) {
  (void)in_sizes; (void)n_in; (void)out_size; (void)ws_size;
  const float* in1   = (const float*)d_in[0];   // [16384][512]
  const float* in2   = (const float*)d_in[1];   // [512][512]
  const float* value = (const float*)d_in[2];   // [512][4096]
  float* out = (float*)d_out;                   // [16384][4096]

  unsigned short* vT   = (unsigned short*)d_ws;  // 4 MB   [4096][512] bf16
  unsigned short* Pb   = vT + 2097152;           // 16 MB  [16384][512] bf16
  unsigned short* in2b = Pb + 8388608;           // 0.5 MB [512][512] bf16

  k_vt<<<dim3(128, 16), dim3(256), 0, stream>>>(value, vT);
  k_cast<<<dim3(256), dim3(256), 0, stream>>>(in2, in2b, 65536);
  k_qk<<<dim3(256), dim3(512), 0, stream>>>(in1, in2b, Pb);
  k_pv<<<dim3(1024), dim3(512), 0, stream>>>(Pb, vT, out);
}